// Round 3
// baseline (308.971 us; speedup 1.0000x reference)
//
#include <hip/hip_runtime.h>

#define V_N 5023
#define V_PAD 5120         // 40*128 vertex padding
#define KTOT 192           // 150 betas + 2 pad + 36 pose_feature + 4 pad
#define B_N 1024
#define NC_REAL 15069      // V*3

// ---- ws offsets (total 6,818,096 <= proven ws floor 6,865,984) ----
#define WS_W     0         // 3 planes * 5120 * 192 bf16 = 5,898,240 B
#define WS_A2    5898240   // 1024*192 bf16 = 393,216 B
#define WS_PART1 6291456   // 30*2250 f32 = 270,000 B
#define WS_PARTJ 6561456   // 30*15 f32 = 1,800 B
#define WS_JS    6563264   // 2250 f32 = 9,000 B
#define WS_JT    6572272   // 15 f32 (+pad)
#define WS_RELT  6572336   // 1024*60 f32 = 245,760 B

typedef __attribute__((ext_vector_type(8))) short bf16x8;
typedef __attribute__((ext_vector_type(4))) float f32x4;

__device__ __forceinline__ unsigned short f2bf(float f) {
  union { float f; unsigned int i; } x; x.f = f;
  unsigned int u = x.i;
  u = (u + 0x7FFFu + ((u >> 16) & 1u)) >> 16;
  return (unsigned short)u;
}

// ---------------- build W planes: Wc[c][v][k] bf16 (5120 x 192 per plane) ----------------
// k 0..149 = shapedirs[(3v+c)][k]; 150,151 = 0; 152..187 = posedirs[k-152][3v+c]; 188..191 = 0
__global__ void k_w2(const float* __restrict__ sd, const float* __restrict__ pd,
                     unsigned short* __restrict__ W) {
  int vc = blockIdx.x * 256 + threadIdx.x;   // grid 60 -> 15360 exact
  int v = vc / 3, c = vc - 3 * v;
  unsigned short* dst = W + ((size_t)c * V_PAD + v) * KTOT;
  if (vc < NC_REAL) {
    for (int k = 0; k < 150; k++) dst[k] = f2bf(sd[(size_t)vc * 150 + k]);
    dst[150] = 0; dst[151] = 0;
    for (int kk = 0; kk < 36; kk++) dst[152 + kk] = f2bf(pd[(size_t)kk * NC_REAL + vc]);
    for (int k = 188; k < 192; k++) dst[k] = 0;
  } else {
    for (int k = 0; k < 192; k++) dst[k] = 0;
  }
}

// ---------------- A2 rows k=0..151: betas bf16, m-major k-contig ----------------
__global__ void k_a2(const float* __restrict__ shp, const float* __restrict__ expr,
                     unsigned short* __restrict__ A2) {
  int g = blockIdx.x * 256 + threadIdx.x;   // grid 304 -> 1024*76 exact
  int b = g / 76, u = g - b * 76;           // u pairs: k = 2u, 2u+1 (k < 152)
  int k0 = 2 * u, k1 = 2 * u + 1;
  float f0 = 0.f, f1 = 0.f;
  if (k0 < 100) f0 = shp[b * 100 + k0]; else if (k0 < 150) f0 = expr[b * 50 + k0 - 100];
  if (k1 < 100) f1 = shp[b * 100 + k1]; else if (k1 < 150) f1 = expr[b * 50 + k1 - 100];
  unsigned int w = (unsigned int)f2bf(f0) | ((unsigned int)f2bf(f1) << 16);
  ((unsigned int*)A2)[b * 96 + u] = w;
}

// ---------------- JS partials: coalesced over k, uniform jreg ----------------
__global__ void k_js1(const float* __restrict__ jreg, const float* __restrict__ sd,
                      const float* __restrict__ vt,
                      float* __restrict__ part1, float* __restrict__ partJ) {
  int blk = blockIdx.x;                     // 30 blocks
  int t = threadIdx.x;
  int vs = blk * 168, ve = vs + 168; if (ve > V_N) ve = V_N;
  if (t < 150) {
    float acc[5][3];
    #pragma unroll
    for (int j = 0; j < 5; j++)
      #pragma unroll
      for (int c = 0; c < 3; c++) acc[j][c] = 0.f;
    for (int v = vs; v < ve; v++) {
      float jr[5];
      #pragma unroll
      for (int j = 0; j < 5; j++) jr[j] = jreg[j * V_N + v];
      #pragma unroll
      for (int c = 0; c < 3; c++) {
        float s = sd[(size_t)(3 * v + c) * 150 + t];
        #pragma unroll
        for (int j = 0; j < 5; j++) acc[j][c] += jr[j] * s;
      }
    }
    #pragma unroll
    for (int j = 0; j < 5; j++)
      #pragma unroll
      for (int c = 0; c < 3; c++)
        part1[(size_t)blk * 2250 + (j * 3 + c) * 150 + t] = acc[j][c];
  } else if (t >= 160 && t < 175) {
    int j = (t - 160) / 3, c = (t - 160) % 3;
    float a = 0.f;
    for (int v = vs; v < ve; v++) a += jreg[j * V_N + v] * vt[3 * v + c];
    partJ[blk * 15 + (t - 160)] = a;
  }
}

__global__ void k_js2(const float* __restrict__ part1, const float* __restrict__ partJ,
                      float* __restrict__ JS, float* __restrict__ Jt) {
  int t = threadIdx.x;                      // 1 block x 256
  for (int u = t; u < 2250; u += 256) {
    float s = 0.f;
    for (int blk = 0; blk < 30; blk++) s += part1[(size_t)blk * 2250 + u];
    JS[u] = s;                              // layout [(j*3+c)*150 + k]
  }
  if (t < 15) {
    float s = 0.f;
    for (int blk = 0; blk < 30; blk++) s += partJ[blk * 15 + t];
    Jt[t] = s;
  }
}

// ---------------- per-batch: rodrigues, joints, chain, rel transforms, pose feature ----------------
__device__ __forceinline__ void rodrigues(const float* p, float* R) {
  float x = p[0], y = p[1], z = p[2];
  float xa = x + 1e-8f, ya = y + 1e-8f, za = z + 1e-8f;
  float angle = sqrtf(xa * xa + ya * ya + za * za);
  float inv = 1.0f / angle;
  float rx = x * inv, ry = y * inv, rz = z * inv;
  float c = cosf(angle), s = sinf(angle), t1 = 1.0f - c;
  float K[9] = {0.f, -rz, ry, rz, 0.f, -rx, -ry, rx, 0.f};
  float KK[9];
  #pragma unroll
  for (int i = 0; i < 3; i++)
    #pragma unroll
    for (int j = 0; j < 3; j++) {
      float a = 0.f;
      #pragma unroll
      for (int k = 0; k < 3; k++) a += K[i * 3 + k] * K[k * 3 + j];
      KK[i * 3 + j] = a;
    }
  #pragma unroll
  for (int i = 0; i < 9; i++) R[i] = s * K[i] + t1 * KK[i];
  R[0] += 1.f; R[4] += 1.f; R[8] += 1.f;
}

__global__ void k_pose(const float* __restrict__ pose,
                       const float* __restrict__ neck,
                       const float* __restrict__ eye,
                       const float* __restrict__ shp,
                       const float* __restrict__ expr,
                       const float* __restrict__ JS,
                       const float* __restrict__ Jt,
                       unsigned short* __restrict__ A2,
                       float* __restrict__ relT) {
  int b = blockIdx.x * 64 + threadIdx.x;    // grid 16 x 64 -> 1024 exact
  float fp[15];
  fp[0] = pose[b * 6 + 0]; fp[1] = pose[b * 6 + 1]; fp[2] = pose[b * 6 + 2];
  fp[3] = neck[0]; fp[4] = neck[1]; fp[5] = neck[2];
  fp[6] = pose[b * 6 + 3]; fp[7] = pose[b * 6 + 4]; fp[8] = pose[b * 6 + 5];
  #pragma unroll
  for (int i = 0; i < 6; i++) fp[9 + i] = eye[i];
  float R[5][9];
  #pragma unroll
  for (int j = 0; j < 5; j++) rodrigues(&fp[j * 3], R[j]);
  float J[5][3];
  #pragma unroll
  for (int j = 0; j < 5; j++)
    #pragma unroll
    for (int c = 0; c < 3; c++) J[j][c] = Jt[j * 3 + c];
  for (int k = 0; k < 150; k++) {
    float be = (k < 100) ? shp[b * 100 + k] : expr[b * 50 + k - 100];
    #pragma unroll
    for (int j = 0; j < 5; j++)
      #pragma unroll
      for (int c = 0; c < 3; c++) J[j][c] += be * JS[(j * 3 + c) * 150 + k];
  }
  float rel[5][3];
  #pragma unroll
  for (int c = 0; c < 3; c++) {
    rel[0][c] = J[0][c];
    rel[1][c] = J[1][c] - J[0][c];
    rel[2][c] = J[2][c] - J[1][c];
    rel[3][c] = J[3][c] - J[1][c];
    rel[4][c] = J[4][c] - J[1][c];
  }
  float GR[5][9], Gt[5][3];
  #pragma unroll
  for (int i = 0; i < 9; i++) GR[0][i] = R[0][i];
  #pragma unroll
  for (int c = 0; c < 3; c++) Gt[0][c] = rel[0][c];
  const int parent[5] = {0, 0, 1, 1, 1};
  #pragma unroll
  for (int j = 1; j < 5; j++) {
    int p = parent[j];
    #pragma unroll
    for (int r = 0; r < 3; r++)
      #pragma unroll
      for (int c = 0; c < 3; c++) {
        float a = 0.f;
        #pragma unroll
        for (int k = 0; k < 3; k++) a += GR[p][r * 3 + k] * R[j][k * 3 + c];
        GR[j][r * 3 + c] = a;
      }
    #pragma unroll
    for (int r = 0; r < 3; r++) {
      float a = Gt[p][r];
      #pragma unroll
      for (int k = 0; k < 3; k++) a += GR[p][r * 3 + k] * rel[j][k];
      Gt[j][r] = a;
    }
  }
  #pragma unroll
  for (int j = 0; j < 5; j++) {
    #pragma unroll
    for (int r = 0; r < 3; r++) {
      float a = 0.f;
      #pragma unroll
      for (int k = 0; k < 3; k++) a += GR[j][r * 3 + k] * J[j][k];
      float tr = Gt[j][r] - a;
      #pragma unroll
      for (int c = 0; c < 3; c++) relT[b * 60 + j * 12 + r * 4 + c] = GR[j][r * 3 + c];
      relT[b * 60 + j * 12 + r * 4 + 3] = tr;
    }
  }
  // pose feature -> A2 rows 152..187 bf16, rows 188..191 zero
  #pragma unroll
  for (int j = 1; j < 5; j++)
    #pragma unroll
    for (int r = 0; r < 3; r++)
      #pragma unroll
      for (int c = 0; c < 3; c++) {
        int kk = (j - 1) * 9 + r * 3 + c;
        A2[(size_t)b * KTOT + 152 + kk] = f2bf(R[j][r * 3 + c] - ((r == c) ? 1.f : 0.f));
      }
  #pragma unroll
  for (int kk = 36; kk < 40; kk++) A2[(size_t)b * KTOT + 152 + kk] = 0;
}

// ---------------- main: MFMA bf16 GEMM (3 coord planes) + fused LBS epilogue ----------------
// block: 64 batches x 128 vertices; 4 waves: (wm,wn) in 2x2, wave tile 32M x 64N x 3 planes
__global__ __launch_bounds__(256) void k_mfma(
    const unsigned short* __restrict__ W,
    const unsigned short* __restrict__ A2,
    const float* __restrict__ relT,
    const float* __restrict__ vt,
    const float* __restrict__ lbsw,
    float* __restrict__ out) {
  __shared__ unsigned short sA[64 * 40];          // [m][40] (32 k + pad)
  __shared__ unsigned short sB[3 * 128 * 40];     // [c*128+n][40]
  __shared__ float sRel[64 * 60];
  int t = threadIdx.x;
  int wave = t >> 6, lane = t & 63, ln = lane & 15, quad = lane >> 4;
  int wm = wave >> 1, wn = wave & 1;
  int v0 = blockIdx.x * 128, b0 = blockIdx.y * 64;

  // stage relT for this block's 64 batches (first loop barrier orders it)
  for (int i = t; i < 3840; i += 256) sRel[i] = relT[(size_t)b0 * 60 + i];

  f32x4 acc[3][2][4];
  #pragma unroll
  for (int c = 0; c < 3; c++)
    #pragma unroll
    for (int mt = 0; mt < 2; mt++)
      #pragma unroll
      for (int nt = 0; nt < 4; nt++) {
        acc[c][mt][nt].x = 0.f; acc[c][mt][nt].y = 0.f;
        acc[c][mt][nt].z = 0.f; acc[c][mt][nt].w = 0.f;
      }

  for (int kc = 0; kc < 6; kc++) {
    // stage A tile: 64 rows x 64B
    {
      int row = t >> 2, part = t & 3;
      const float4* src = (const float4*)(A2 + (size_t)(b0 + row) * KTOT + kc * 32 + part * 8);
      *(float4*)&sA[row * 40 + part * 8] = *src;
    }
    // stage B tiles: 384 rows x 64B
    #pragma unroll
    for (int i = 0; i < 6; i++) {
      int task = i * 256 + t;
      int row = task >> 2, part = task & 3;
      int c = row >> 7, n = row & 127;
      const float4* src = (const float4*)(W + ((size_t)c * V_PAD + v0 + n) * KTOT + kc * 32 + part * 8);
      *(float4*)&sB[(c * 128 + n) * 40 + part * 8] = *src;
    }
    __syncthreads();
    bf16x8 af0 = *(const bf16x8*)&sA[(wm * 32 + ln) * 40 + quad * 8];
    bf16x8 af1 = *(const bf16x8*)&sA[(wm * 32 + 16 + ln) * 40 + quad * 8];
    #pragma unroll
    for (int c = 0; c < 3; c++)
      #pragma unroll
      for (int nt = 0; nt < 4; nt++) {
        bf16x8 bf = *(const bf16x8*)&sB[(c * 128 + wn * 64 + nt * 16 + ln) * 40 + quad * 8];
        acc[c][0][nt] = __builtin_amdgcn_mfma_f32_16x16x32_bf16(af0, bf, acc[c][0][nt], 0, 0, 0);
        acc[c][1][nt] = __builtin_amdgcn_mfma_f32_16x16x32_bf16(af1, bf, acc[c][1][nt], 0, 0, 0);
      }
    __syncthreads();
  }

  // epilogue: lane holds vertex v (col) with all 3 coords; rows = batches
  #pragma unroll
  for (int nt = 0; nt < 4; nt++) {
    int v = v0 + wn * 64 + nt * 16 + ln;
    bool ok = v < V_N;
    float vtx = 0.f, vty = 0.f, vtz = 0.f;
    float w5[5] = {0.f, 0.f, 0.f, 0.f, 0.f};
    if (ok) {
      vtx = vt[3 * v]; vty = vt[3 * v + 1]; vtz = vt[3 * v + 2];
      #pragma unroll
      for (int j = 0; j < 5; j++) w5[j] = lbsw[v * 5 + j];
    }
    #pragma unroll
    for (int mt = 0; mt < 2; mt++)
      #pragma unroll
      for (int reg = 0; reg < 4; reg++) {
        int bl = wm * 32 + mt * 16 + quad * 4 + reg;
        float px = acc[0][mt][nt][reg] + vtx;
        float py = acc[1][mt][nt][reg] + vty;
        float pz = acc[2][mt][nt][reg] + vtz;
        float ox = 0.f, oy = 0.f, oz = 0.f;
        const float* M = &sRel[bl * 60];
        #pragma unroll
        for (int j = 0; j < 5; j++) {
          const float* m = M + j * 12;
          float q0 = m[0] * px + m[1] * py + m[2] * pz + m[3];
          float q1 = m[4] * px + m[5] * py + m[6] * pz + m[7];
          float q2 = m[8] * px + m[9] * py + m[10] * pz + m[11];
          ox += w5[j] * q0; oy += w5[j] * q1; oz += w5[j] * q2;
        }
        if (ok) {
          size_t off = (size_t)(b0 + bl) * NC_REAL + (size_t)3 * v;
          out[off] = ox; out[off + 1] = oy; out[off + 2] = oz;
        }
      }
  }
}

// ---------------- landmarks gather ----------------
__global__ void k_lmk(const float* __restrict__ verts,
                      const int* __restrict__ land,
                      float* __restrict__ lm) {
  int g = blockIdx.x * 256 + threadIdx.x;   // grid 816 -> 1024*68*3 exact
  int b = g / 204;
  int r = g - b * 204;
  int i = r / 3, c = r - i * 3;
  lm[g] = verts[(size_t)b * NC_REAL + (size_t)land[i] * 3 + c];
}

extern "C" void kernel_launch(void* const* d_in, const int* in_sizes, int n_in,
                              void* d_out, int out_size, void* d_ws, size_t ws_size,
                              hipStream_t stream) {
  const float* shp  = (const float*)d_in[0];
  const float* expr = (const float*)d_in[1];
  const float* pose = (const float*)d_in[2];
  const int*   land = (const int*)d_in[3];
  const float* vt   = (const float*)d_in[4];
  const float* sd   = (const float*)d_in[5];
  const float* pd   = (const float*)d_in[6];
  const float* jreg = (const float*)d_in[7];
  const float* lbsw = (const float*)d_in[8];
  const float* eye  = (const float*)d_in[9];
  const float* neck = (const float*)d_in[10];
  char* ws = (char*)d_ws;
  unsigned short* W    = (unsigned short*)(ws + WS_W);
  unsigned short* A2   = (unsigned short*)(ws + WS_A2);
  float* part1 = (float*)(ws + WS_PART1);
  float* partJ = (float*)(ws + WS_PARTJ);
  float* JS    = (float*)(ws + WS_JS);
  float* Jt    = (float*)(ws + WS_JT);
  float* relT  = (float*)(ws + WS_RELT);
  float* outv = (float*)d_out;
  float* outl = outv + (size_t)B_N * NC_REAL;

  hipLaunchKernelGGL(k_w2,   dim3(60),      dim3(256), 0, stream, sd, pd, W);
  hipLaunchKernelGGL(k_a2,   dim3(304),     dim3(256), 0, stream, shp, expr, A2);
  hipLaunchKernelGGL(k_js1,  dim3(30),      dim3(256), 0, stream, jreg, sd, vt, part1, partJ);
  hipLaunchKernelGGL(k_js2,  dim3(1),       dim3(256), 0, stream, part1, partJ, JS, Jt);
  hipLaunchKernelGGL(k_pose, dim3(16),      dim3(64),  0, stream, pose, neck, eye, shp, expr, JS, Jt, A2, relT);
  hipLaunchKernelGGL(k_mfma, dim3(40, 16),  dim3(256), 0, stream, W, A2, relT, vt, lbsw, outv);
  hipLaunchKernelGGL(k_lmk,  dim3(816),     dim3(256), 0, stream, outv, land, outl);
}

// Round 4
// 236.726 us; speedup vs baseline: 1.3052x; 1.3052x over previous
//
#include <hip/hip_runtime.h>

#define V_N 5023
#define V_PAD 5120         // 40*128 vertex padding
#define KTOT 192           // 150 betas + 2 pad + 36 pose_feature + 4 pad
#define B_N 1024
#define NC_REAL 15069      // V*3

// ---- ws layout (max 6,804,240 <= proven-working 6,818,096) ----
// W:      0        .. 5,898,240   (3 planes * 5120 * 192 bf16)
// part1:  5,898,240 .. 6,789,240  (99 * 2250 f32)   [dead after k_js2]
// partJ:  6,789,240 .. 6,795,180  (99 * 15 f32)     [dead after k_js2]
// JS:     6,795,180 .. 6,804,180  (2250 f32)
// Jt:     6,804,180 .. 6,804,240  (15 f32)
// A2:     5,898,240 .. 6,291,456  (1024*192 bf16)   [aliases part1; written after k_js2]
// relT:   6,291,456 .. 6,537,216  (1024*60 f32)     [aliases part1; written after k_js2]
#define WS_W     0
#define WS_PART1 5898240
#define WS_PARTJ 6789240
#define WS_JS    6795180
#define WS_JT    6804180
#define WS_A2    5898240
#define WS_RELT  6291456

typedef __attribute__((ext_vector_type(8))) short bf16x8;
typedef __attribute__((ext_vector_type(4))) float f32x4;

__device__ __forceinline__ unsigned short f2bf(float f) {
  union { float f; unsigned int i; } x; x.f = f;
  unsigned int u = x.i;
  u = (u + 0x7FFFu + ((u >> 16) & 1u)) >> 16;
  return (unsigned short)u;
}

// ---------------- zero W (5,898,240 B = 368,640 float4) ----------------
__global__ void k_wzero(float4* __restrict__ W4) {
  int g = blockIdx.x * 256 + threadIdx.x;   // grid 1440 -> exact
  W4[g] = make_float4(0.f, 0.f, 0.f, 0.f);
}

// ---------------- shapedirs -> W k=0..149, coalesced pairs ----------------
__global__ void k_w2a(const float* __restrict__ sd, unsigned int* __restrict__ W32) {
  int g = blockIdx.x * 256 + threadIdx.x;   // grid 4415 covers 15069*75=1,130,175
  if (g >= NC_REAL * 75) return;
  int vc = g / 75, part = g - vc * 75;
  float2 s = *(const float2*)(sd + (size_t)vc * 150 + 2 * part);
  unsigned int w = (unsigned int)f2bf(s.x) | ((unsigned int)f2bf(s.y) << 16);
  int v = vc / 3, c = vc - 3 * v;
  W32[((size_t)c * V_PAD + v) * 96 + part] = w;
}

// ---------------- posedirs -> W k=152..187 via LDS tile transpose ----------------
__global__ void k_w2b(const float* __restrict__ pd, unsigned short* __restrict__ W) {
  __shared__ unsigned short tile[64][38];
  int vc0 = blockIdx.x * 64;                // grid 236 -> covers 15104
  int t = threadIdx.x;
  for (int i = t; i < 2304; i += 256) {     // 36 kk * 64 vc
    int kk = i >> 6, vl = i & 63;
    int vc = vc0 + vl;
    tile[vl][kk] = (vc < NC_REAL) ? f2bf(pd[(size_t)kk * NC_REAL + vc]) : (unsigned short)0;
  }
  __syncthreads();
  for (int i = t; i < 1152; i += 256) {     // 64 rows * 18 u32
    int row = i / 18, part = i - row * 18;
    int vc = vc0 + row;
    if (vc < NC_REAL) {
      int v = vc / 3, c = vc - 3 * v;
      unsigned int w = (unsigned int)tile[row][2 * part] |
                       ((unsigned int)tile[row][2 * part + 1] << 16);
      *((unsigned int*)(W + ((size_t)c * V_PAD + v) * KTOT + 152) + part) = w;
    }
  }
}

// ---------------- JS partials: 198 blocks = 99 v-chunks x 2 k-halves ----------------
__global__ void k_js1(const float* __restrict__ jreg, const float* __restrict__ sd,
                      const float* __restrict__ vt,
                      float* __restrict__ part1, float* __restrict__ partJ) {
  int blk = blockIdx.x;
  int vcidx = blk >> 1, kh = blk & 1;
  int t = threadIdx.x;                      // block 128
  int vs = vcidx * 51, ve = vs + 51; if (ve > V_N) ve = V_N;
  if (t < 75) {
    int k = kh * 75 + t;
    float acc[5][3];
    #pragma unroll
    for (int j = 0; j < 5; j++)
      #pragma unroll
      for (int c = 0; c < 3; c++) acc[j][c] = 0.f;
    #pragma unroll 2
    for (int v = vs; v < ve; v++) {
      float jr[5];
      #pragma unroll
      for (int j = 0; j < 5; j++) jr[j] = jreg[j * V_N + v];
      #pragma unroll
      for (int c = 0; c < 3; c++) {
        float s = sd[(size_t)(3 * v + c) * 150 + k];
        #pragma unroll
        for (int j = 0; j < 5; j++) acc[j][c] += jr[j] * s;
      }
    }
    #pragma unroll
    for (int j = 0; j < 5; j++)
      #pragma unroll
      for (int c = 0; c < 3; c++)
        part1[(size_t)vcidx * 2250 + (j * 3 + c) * 150 + kh * 75 + t] = acc[j][c];
  } else if (kh == 0 && t >= 80 && t < 95) {
    int j = (t - 80) / 3, c = (t - 80) % 3;
    float a = 0.f;
    for (int v = vs; v < ve; v++) a += jreg[j * V_N + v] * vt[3 * v + c];
    partJ[vcidx * 15 + (t - 80)] = a;
  }
}

__global__ void k_js2(const float* __restrict__ part1, const float* __restrict__ partJ,
                      float* __restrict__ JS, float* __restrict__ Jt) {
  int blk = blockIdx.x, t = threadIdx.x;    // grid 10 x 256
  if (blk < 9) {
    int u = blk * 256 + t;
    if (u < 2250) {
      float s = 0.f;
      #pragma unroll 4
      for (int p = 0; p < 99; p++) s += part1[(size_t)p * 2250 + u];
      JS[u] = s;                            // layout [(j*3+c)*150 + k]
    }
  } else if (t < 15) {
    float s = 0.f;
    #pragma unroll 4
    for (int p = 0; p < 99; p++) s += partJ[p * 15 + t];
    Jt[t] = s;
  }
}

// ---------------- A2 rows k=0..151: betas bf16, m-major k-contig ----------------
__global__ void k_a2(const float* __restrict__ shp, const float* __restrict__ expr,
                     unsigned short* __restrict__ A2) {
  int g = blockIdx.x * 256 + threadIdx.x;   // grid 304 -> 1024*76 exact
  int b = g / 76, u = g - b * 76;           // u pairs: k = 2u, 2u+1 (k < 152)
  int k0 = 2 * u, k1 = 2 * u + 1;
  float f0 = 0.f, f1 = 0.f;
  if (k0 < 100) f0 = shp[b * 100 + k0]; else if (k0 < 150) f0 = expr[b * 50 + k0 - 100];
  if (k1 < 100) f1 = shp[b * 100 + k1]; else if (k1 < 150) f1 = expr[b * 50 + k1 - 100];
  unsigned int w = (unsigned int)f2bf(f0) | ((unsigned int)f2bf(f1) << 16);
  ((unsigned int*)A2)[b * 96 + u] = w;
}

// ---------------- per-batch: rodrigues, joints, chain, rel transforms, pose feature ----------------
__device__ __forceinline__ void rodrigues(const float* p, float* R) {
  float x = p[0], y = p[1], z = p[2];
  float xa = x + 1e-8f, ya = y + 1e-8f, za = z + 1e-8f;
  float angle = sqrtf(xa * xa + ya * ya + za * za);
  float inv = 1.0f / angle;
  float rx = x * inv, ry = y * inv, rz = z * inv;
  float c = cosf(angle), s = sinf(angle), t1 = 1.0f - c;
  float K[9] = {0.f, -rz, ry, rz, 0.f, -rx, -ry, rx, 0.f};
  float KK[9];
  #pragma unroll
  for (int i = 0; i < 3; i++)
    #pragma unroll
    for (int j = 0; j < 3; j++) {
      float a = 0.f;
      #pragma unroll
      for (int k = 0; k < 3; k++) a += K[i * 3 + k] * K[k * 3 + j];
      KK[i * 3 + j] = a;
    }
  #pragma unroll
  for (int i = 0; i < 9; i++) R[i] = s * K[i] + t1 * KK[i];
  R[0] += 1.f; R[4] += 1.f; R[8] += 1.f;
}

__global__ __launch_bounds__(64) void k_pose(
    const float* __restrict__ pose, const float* __restrict__ neck,
    const float* __restrict__ eye, const float* __restrict__ shp,
    const float* __restrict__ expr, const float* __restrict__ JS,
    const float* __restrict__ Jt, unsigned short* __restrict__ A2,
    float* __restrict__ relT) {
  __shared__ float sBet[150 * 64];
  __shared__ float sJS[2250];
  int t = threadIdx.x;                      // grid 16 x 64
  int b0 = blockIdx.x * 64;
  for (int i = t; i < 6400; i += 64) {      // shp: 64 rows x 100, coalesced
    int row = i / 100, col = i - row * 100;
    sBet[col * 64 + row] = shp[(size_t)(b0 + row) * 100 + col];
  }
  for (int i = t; i < 3200; i += 64) {      // expr: 64 rows x 50, coalesced
    int row = i / 50, col = i - row * 50;
    sBet[(100 + col) * 64 + row] = expr[(size_t)(b0 + row) * 50 + col];
  }
  for (int i = t; i < 2250; i += 64) sJS[i] = JS[i];
  __syncthreads();
  int b = b0 + t;
  float fp[15];
  fp[0] = pose[b * 6 + 0]; fp[1] = pose[b * 6 + 1]; fp[2] = pose[b * 6 + 2];
  fp[3] = neck[0]; fp[4] = neck[1]; fp[5] = neck[2];
  fp[6] = pose[b * 6 + 3]; fp[7] = pose[b * 6 + 4]; fp[8] = pose[b * 6 + 5];
  #pragma unroll
  for (int i = 0; i < 6; i++) fp[9 + i] = eye[i];
  float R[5][9];
  #pragma unroll
  for (int j = 0; j < 5; j++) rodrigues(&fp[j * 3], R[j]);
  float J[5][3];
  #pragma unroll
  for (int j = 0; j < 5; j++)
    #pragma unroll
    for (int c = 0; c < 3; c++) J[j][c] = Jt[j * 3 + c];
  for (int k = 0; k < 150; k++) {
    float be = sBet[k * 64 + t];
    #pragma unroll
    for (int j = 0; j < 5; j++)
      #pragma unroll
      for (int c = 0; c < 3; c++) J[j][c] += be * sJS[(j * 3 + c) * 150 + k];
  }
  float rel[5][3];
  #pragma unroll
  for (int c = 0; c < 3; c++) {
    rel[0][c] = J[0][c];
    rel[1][c] = J[1][c] - J[0][c];
    rel[2][c] = J[2][c] - J[1][c];
    rel[3][c] = J[3][c] - J[1][c];
    rel[4][c] = J[4][c] - J[1][c];
  }
  float GR[5][9], Gt[5][3];
  #pragma unroll
  for (int i = 0; i < 9; i++) GR[0][i] = R[0][i];
  #pragma unroll
  for (int c = 0; c < 3; c++) Gt[0][c] = rel[0][c];
  const int parent[5] = {0, 0, 1, 1, 1};
  #pragma unroll
  for (int j = 1; j < 5; j++) {
    int p = parent[j];
    #pragma unroll
    for (int r = 0; r < 3; r++)
      #pragma unroll
      for (int c = 0; c < 3; c++) {
        float a = 0.f;
        #pragma unroll
        for (int k = 0; k < 3; k++) a += GR[p][r * 3 + k] * R[j][k * 3 + c];
        GR[j][r * 3 + c] = a;
      }
    #pragma unroll
    for (int r = 0; r < 3; r++) {
      float a = Gt[p][r];
      #pragma unroll
      for (int k = 0; k < 3; k++) a += GR[p][r * 3 + k] * rel[j][k];
      Gt[j][r] = a;
    }
  }
  #pragma unroll
  for (int j = 0; j < 5; j++) {
    #pragma unroll
    for (int r = 0; r < 3; r++) {
      float a = 0.f;
      #pragma unroll
      for (int k = 0; k < 3; k++) a += GR[j][r * 3 + k] * J[j][k];
      float tr = Gt[j][r] - a;
      #pragma unroll
      for (int c = 0; c < 3; c++) relT[b * 60 + j * 12 + r * 4 + c] = GR[j][r * 3 + c];
      relT[b * 60 + j * 12 + r * 4 + 3] = tr;
    }
  }
  #pragma unroll
  for (int j = 1; j < 5; j++)
    #pragma unroll
    for (int r = 0; r < 3; r++)
      #pragma unroll
      for (int c = 0; c < 3; c++) {
        int kk = (j - 1) * 9 + r * 3 + c;
        A2[(size_t)b * KTOT + 152 + kk] = f2bf(R[j][r * 3 + c] - ((r == c) ? 1.f : 0.f));
      }
  #pragma unroll
  for (int kk = 36; kk < 40; kk++) A2[(size_t)b * KTOT + 152 + kk] = 0;
}

// ---------------- main: MFMA bf16 GEMM (3 coord planes) + fused LBS epilogue ----------------
__global__ __launch_bounds__(256) void k_mfma(
    const unsigned short* __restrict__ W,
    const unsigned short* __restrict__ A2,
    const float* __restrict__ relT,
    const float* __restrict__ vt,
    const float* __restrict__ lbsw,
    float* __restrict__ out) {
  __shared__ unsigned short sA[64 * 40];          // [m][40] (32 k + pad)
  __shared__ unsigned short sB[3 * 128 * 40];     // [c*128+n][40]
  __shared__ float sRel[64 * 60];
  int t = threadIdx.x;
  int wave = t >> 6, lane = t & 63, ln = lane & 15, quad = lane >> 4;
  int wm = wave >> 1, wn = wave & 1;
  int v0 = blockIdx.x * 128, b0 = blockIdx.y * 64;

  for (int i = t; i < 3840; i += 256) sRel[i] = relT[(size_t)b0 * 60 + i];

  f32x4 acc[3][2][4];
  #pragma unroll
  for (int c = 0; c < 3; c++)
    #pragma unroll
    for (int mt = 0; mt < 2; mt++)
      #pragma unroll
      for (int nt = 0; nt < 4; nt++) {
        acc[c][mt][nt].x = 0.f; acc[c][mt][nt].y = 0.f;
        acc[c][mt][nt].z = 0.f; acc[c][mt][nt].w = 0.f;
      }

  for (int kc = 0; kc < 6; kc++) {
    {
      int row = t >> 2, part = t & 3;
      const float4* src = (const float4*)(A2 + (size_t)(b0 + row) * KTOT + kc * 32 + part * 8);
      *(float4*)&sA[row * 40 + part * 8] = *src;
    }
    #pragma unroll
    for (int i = 0; i < 6; i++) {
      int task = i * 256 + t;
      int row = task >> 2, part = task & 3;
      int c = row >> 7, n = row & 127;
      const float4* src = (const float4*)(W + ((size_t)c * V_PAD + v0 + n) * KTOT + kc * 32 + part * 8);
      *(float4*)&sB[(c * 128 + n) * 40 + part * 8] = *src;
    }
    __syncthreads();
    bf16x8 af0 = *(const bf16x8*)&sA[(wm * 32 + ln) * 40 + quad * 8];
    bf16x8 af1 = *(const bf16x8*)&sA[(wm * 32 + 16 + ln) * 40 + quad * 8];
    #pragma unroll
    for (int c = 0; c < 3; c++)
      #pragma unroll
      for (int nt = 0; nt < 4; nt++) {
        bf16x8 bf = *(const bf16x8*)&sB[(c * 128 + wn * 64 + nt * 16 + ln) * 40 + quad * 8];
        acc[c][0][nt] = __builtin_amdgcn_mfma_f32_16x16x32_bf16(af0, bf, acc[c][0][nt], 0, 0, 0);
        acc[c][1][nt] = __builtin_amdgcn_mfma_f32_16x16x32_bf16(af1, bf, acc[c][1][nt], 0, 0, 0);
      }
    __syncthreads();
  }

  #pragma unroll
  for (int nt = 0; nt < 4; nt++) {
    int v = v0 + wn * 64 + nt * 16 + ln;
    bool ok = v < V_N;
    float vtx = 0.f, vty = 0.f, vtz = 0.f;
    float w5[5] = {0.f, 0.f, 0.f, 0.f, 0.f};
    if (ok) {
      vtx = vt[3 * v]; vty = vt[3 * v + 1]; vtz = vt[3 * v + 2];
      #pragma unroll
      for (int j = 0; j < 5; j++) w5[j] = lbsw[v * 5 + j];
    }
    #pragma unroll
    for (int mt = 0; mt < 2; mt++)
      #pragma unroll
      for (int reg = 0; reg < 4; reg++) {
        int bl = wm * 32 + mt * 16 + quad * 4 + reg;
        float px = acc[0][mt][nt][reg] + vtx;
        float py = acc[1][mt][nt][reg] + vty;
        float pz = acc[2][mt][nt][reg] + vtz;
        float ox = 0.f, oy = 0.f, oz = 0.f;
        const float* M = &sRel[bl * 60];
        #pragma unroll
        for (int j = 0; j < 5; j++) {
          const float* m = M + j * 12;
          float q0 = m[0] * px + m[1] * py + m[2] * pz + m[3];
          float q1 = m[4] * px + m[5] * py + m[6] * pz + m[7];
          float q2 = m[8] * px + m[9] * py + m[10] * pz + m[11];
          ox += w5[j] * q0; oy += w5[j] * q1; oz += w5[j] * q2;
        }
        if (ok) {
          size_t off = (size_t)(b0 + bl) * NC_REAL + (size_t)3 * v;
          out[off] = ox; out[off + 1] = oy; out[off + 2] = oz;
        }
      }
  }
}

// ---------------- landmarks gather ----------------
__global__ void k_lmk(const float* __restrict__ verts,
                      const int* __restrict__ land,
                      float* __restrict__ lm) {
  int g = blockIdx.x * 256 + threadIdx.x;   // grid 816 -> 1024*68*3 exact
  int b = g / 204;
  int r = g - b * 204;
  int i = r / 3, c = r - i * 3;
  lm[g] = verts[(size_t)b * NC_REAL + (size_t)land[i] * 3 + c];
}

extern "C" void kernel_launch(void* const* d_in, const int* in_sizes, int n_in,
                              void* d_out, int out_size, void* d_ws, size_t ws_size,
                              hipStream_t stream) {
  const float* shp  = (const float*)d_in[0];
  const float* expr = (const float*)d_in[1];
  const float* pose = (const float*)d_in[2];
  const int*   land = (const int*)d_in[3];
  const float* vt   = (const float*)d_in[4];
  const float* sd   = (const float*)d_in[5];
  const float* pd   = (const float*)d_in[6];
  const float* jreg = (const float*)d_in[7];
  const float* lbsw = (const float*)d_in[8];
  const float* eye  = (const float*)d_in[9];
  const float* neck = (const float*)d_in[10];
  char* ws = (char*)d_ws;
  unsigned short* W    = (unsigned short*)(ws + WS_W);
  float* part1 = (float*)(ws + WS_PART1);
  float* partJ = (float*)(ws + WS_PARTJ);
  float* JS    = (float*)(ws + WS_JS);
  float* Jt    = (float*)(ws + WS_JT);
  unsigned short* A2   = (unsigned short*)(ws + WS_A2);
  float* relT  = (float*)(ws + WS_RELT);
  float* outv = (float*)d_out;
  float* outl = outv + (size_t)B_N * NC_REAL;

  hipLaunchKernelGGL(k_wzero, dim3(1440),    dim3(256), 0, stream, (float4*)W);
  hipLaunchKernelGGL(k_w2a,   dim3(4415),    dim3(256), 0, stream, sd, (unsigned int*)W);
  hipLaunchKernelGGL(k_w2b,   dim3(236),     dim3(256), 0, stream, pd, W);
  hipLaunchKernelGGL(k_js1,   dim3(198),     dim3(128), 0, stream, jreg, sd, vt, part1, partJ);
  hipLaunchKernelGGL(k_js2,   dim3(10),      dim3(256), 0, stream, part1, partJ, JS, Jt);
  hipLaunchKernelGGL(k_a2,    dim3(304),     dim3(256), 0, stream, shp, expr, A2);
  hipLaunchKernelGGL(k_pose,  dim3(16),      dim3(64),  0, stream, pose, neck, eye, shp, expr, JS, Jt, A2, relT);
  hipLaunchKernelGGL(k_mfma,  dim3(40, 16),  dim3(256), 0, stream, W, A2, relT, vt, lbsw, outv);
  hipLaunchKernelGGL(k_lmk,   dim3(816),     dim3(256), 0, stream, outv, land, outl);
}